// Round 7
// baseline (337.615 us; speedup 1.0000x reference)
//
#include <hip/hip_runtime.h>
#include <hip/hip_fp16.h>

typedef _Float16 half2_t __attribute__((ext_vector_type(2)));
typedef _Float16 half4_t __attribute__((ext_vector_type(4)));
typedef _Float16 half8_t __attribute__((ext_vector_type(8)));
typedef float   float4_t __attribute__((ext_vector_type(4)));
typedef float  float16_t __attribute__((ext_vector_type(16)));

static __device__ __forceinline__ half2_t cvt_pk(float a, float b) {
    return __builtin_bit_cast(half2_t, __builtin_amdgcn_cvt_pkrtz(a, b));
}
static __device__ __forceinline__ half4_t cvt_pk4(float a, float b, float c, float d) {
    half2_t lo = cvt_pk(a, b), hi = cvt_pk(c, d);
    half4_t r;
    r[0] = lo[0]; r[1] = lo[1]; r[2] = hi[0]; r[3] = hi[1];
    return r;
}
static __device__ __forceinline__ half8_t cvt_pk8(const float4& a, const float4& b) {
    half4_t lo = cvt_pk4(a.x, a.y, a.z, a.w);
    half4_t hi = cvt_pk4(b.x, b.y, b.z, b.w);
    return __builtin_shufflevector(lo, hi, 0, 1, 2, 3, 4, 5, 6, 7);
}
static __device__ __forceinline__ half8_t join8(half4_t lo, half4_t hi) {
    return __builtin_shufflevector(lo, hi, 0, 1, 2, 3, 4, 5, 6, 7);
}
static __device__ __forceinline__ float f3(float a, float b, float c) {
    return fmaxf(fmaxf(a, b), c);   // clang fuses to v_max3_f32 (T17)
}

namespace {
constexpr int kB       = 16;    // batch
constexpr int kL       = 4096;  // Lq == Lk
constexpr int kD       = 64;    // head dim
constexpr int kQTile   = 128;   // 4 waves x 32 q-rows
constexpr int kBK      = 64;    // keys per tile
constexpr int kTiles   = kL / kBK;          // 64 key-tiles per batch
constexpr int kSplit   = 2;                 // K-split (grid 1024)
constexpr int kTilesHf = kTiles / kSplit;   // 32 key-tiles per half
constexpr int kTileH   = kBK * kD;          // 4096 halves per tile image
constexpr int kKStride = 72;    // Ksh stride (halves): b128 reads, even bank groups
constexpr int kVStride = 72;    // Vsh stride (halves): b128 reads/writes
constexpr size_t kWsHalves = (size_t)kB * kTiles * kTileH;  // 8 MB per operand
constexpr size_t kOHalves  = (size_t)kB * kL * kD;          // 8 MB fp16 partial O
}

// v18: v14 base (97.4us best) + T15 one-tile software pipeline.
// R6 post-mortem: V-direct-from-global exceeds per-CU L2 bandwidth
// (40KB/block-tile = 87B/cy/CU vs ~56 ceiling) -> LDS staging is a required
// 4x bandwidth amplifier; v15/v16/v17 family closed. v14 residual: ~30%
// issue bubbles (MFMA in two bursts split by serial softmax; post-barrier
// kf->QK->max stall). Fix: carry pf(t-1) [16 VGPR] + vfr(t-1) [32 VGPR];
// per iter: QK(t) then PV(t-1) back-to-back (register-only PV feeds the
// MFMA pipe right after the barrier), THEN rescale (O includes PV(t-1) at
// old scale -> alpha to new scale: exact online softmax), softmax/pack
// interleaved with vfr(t) reads as S dies (peak ~122 VGPR < 128 cap; v15's
// spill came from holding V live ACROSS softmax). Iter 0: PV on zeroed
// pf/vfr (branch-free); epilogue PV(last). LDS/barrier discipline = v14.

__global__ __launch_bounds__(256) void prep_kv(const float* __restrict__ K,
                                               const float* __restrict__ V,
                                               _Float16* __restrict__ Kws,
                                               _Float16* __restrict__ Vws)
{
    int blk = blockIdx.x;
    const int tid = threadIdx.x;
    if (blk < kB * kTiles) {
        // K image: fp16 row-major per tile, with key bits 2<->3 swapped so the
        // 32x32 MFMA S-reg order matches the PV B-operand key order.
        const float* src = K + (size_t)blk * kTileH;
        _Float16* dst = Kws + (size_t)blk * kTileH;
#pragma unroll
        for (int i = 0; i < 2; ++i) {
            const int task = tid + 256 * i;
            const int row  = task >> 3;       // dst physical row 0..63
            const int g    = task & 7;
            const int srow = (row & ~12) | ((row & 4) << 1) | ((row & 8) >> 1);
            const float* p = src + srow * kD + g * 8;
            const float4 a  = *(const float4*)p;
            const float4 b2 = *(const float4*)(p + 4);
            *(half8_t*)(dst + task * 8) = cvt_pk8(a, b2);
        }
    } else {
        // V^T image: [c8 chunk][d][8 keys] halves; natural key order
        blk -= kB * kTiles;
        const float* src = V + (size_t)blk * kTileH;   // [key][d]
        _Float16* dst = Vws + (size_t)blk * kTileH;
        const int d  = tid & 63;
        const int vw = tid >> 6;
#pragma unroll
        for (int i = 0; i < 2; ++i) {
            const int c8 = vw * 2 + i;
            const int k0 = c8 * 8;
            float p[8];
#pragma unroll
            for (int j = 0; j < 8; ++j) p[j] = src[(k0 + j) * kD + d];
            half4_t lo = cvt_pk4(p[0], p[1], p[2], p[3]);
            half4_t hi = cvt_pk4(p[4], p[5], p[6], p[7]);
            *(half8_t*)(dst + (c8 * 64 + d) * 8) = join8(lo, hi);
        }
    }
}

__global__ __launch_bounds__(256, 4)
void fa_fwd(const float* __restrict__ Q, const _Float16* __restrict__ Kws,
            const _Float16* __restrict__ Vws, const float* __restrict__ scale_ptr,
            float* __restrict__ Out, _Float16* __restrict__ O2ws,
            float* __restrict__ Mlws)
{
    __shared__ __align__(16) _Float16 Ksh[2][kBK * kKStride];  // [buf][key_phys][d]
    __shared__ __align__(16) _Float16 Vsh[2][kD * kVStride];   // [buf][d][key] (V^T)

    const int tid  = threadIdx.x;
    const int wave = tid >> 6;
    const int lane = tid & 63;
    const int l31  = lane & 31;   // q-row (QK B / PV B col); key row (QK A); d row (PV A)
    const int hi   = lane >> 5;   // half-select: k = hi*8 + j

    const int b  = blockIdx.y;
    const int hf = blockIdx.z;    // key-split half
    const int q0 = blockIdx.x * kQTile + wave * 32;

    // staging decompositions (match image layouts)
    const int task0 = tid, task1 = tid + 256;          // K: row=task>>3, g=task&7
    const int vd = tid & 63;                           // V: this thread's d
    const int vw = tid >> 6;                           // V: chunk pair base
    const int koff0 = (task0 >> 3) * kKStride + (task0 & 7) * 8;
    const int koff1 = (task1 >> 3) * kKStride + (task1 & 7) * 8;
    const int voff0 = vd * kVStride + (vw * 2 + 0) * 8;
    const int voff1 = vd * kVStride + (vw * 2 + 1) * 8;

    const float qscale = 1.4426950408889634f / scale_ptr[0];

    const float*    Qb = Q   + (size_t)b * kL * kD;
    const _Float16* Kt = Kws + ((size_t)b * kTiles + (size_t)hf * kTilesHf) * kTileH;
    const _Float16* Vt = Vws + ((size_t)b * kTiles + (size_t)hf * kTilesHf) * kTileH;

    // ---- Q fragments (B-operand 32x32x16: n=l31=qrow, k=hi*8+j, d=kd*16+k) ----
    half8_t qfrag[4];
    {
        const float* qrow = Qb + (size_t)(q0 + l31) * kD;
#pragma unroll
        for (int kd = 0; kd < 4; ++kd) {
            const float* p = qrow + kd * 16 + hi * 8;
            half8_t h;
#pragma unroll
            for (int j = 0; j < 8; ++j) h[j] = (_Float16)(p[j] * qscale);
            qfrag[kd] = h;
        }
    }

    // O^T accumulators: col=l31=q, row=d=(r&3)+8*(r>>2)+4*hi (+32*dt)
    float16_t O[2];
    O[0] = (float16_t)0.0f;
    O[1] = (float16_t)0.0f;
    float m_run = -__builtin_inff();
    float l_run = 0.0f;   // lane-local (this half's keys); pair-combined in epilogue
    const float16_t Zc = (float16_t)0.0f;

    // ---- carried pipeline state: P(t-1) fragments + V(t-1) fragments ----
    const half8_t hz = (half8_t)(_Float16)0.0f;
    half8_t pf[4]  = {hz, hz, hz, hz};     // 16 VGPRs
    half8_t vfr0[4] = {hz, hz, hz, hz};    // 16 VGPRs (d-rows 0..31)
    half8_t vfr1[4] = {hz, hz, hz, hz};    // 16 VGPRs (d-rows 32..63)

    // ---- prologue: stage tile 0 into buf0, prefetch tile 1 into regs ----
    half8_t kp[2], vp[2];
    kp[0] = *(const half8_t*)(Kt + task0 * 8);
    kp[1] = *(const half8_t*)(Kt + task1 * 8);
    vp[0] = *(const half8_t*)(Vt + ((vw * 2 + 0) * 64 + vd) * 8);
    vp[1] = *(const half8_t*)(Vt + ((vw * 2 + 1) * 64 + vd) * 8);
    *(half8_t*)(&Ksh[0][koff0]) = kp[0];
    *(half8_t*)(&Ksh[0][koff1]) = kp[1];
    *(half8_t*)(&Vsh[0][voff0]) = vp[0];
    *(half8_t*)(&Vsh[0][voff1]) = vp[1];
    {
        const _Float16* kn = Kt + (size_t)1 * kTileH;
        const _Float16* vn = Vt + (size_t)1 * kTileH;
        kp[0] = *(const half8_t*)(kn + task0 * 8);
        kp[1] = *(const half8_t*)(kn + task1 * 8);
        vp[0] = *(const half8_t*)(vn + ((vw * 2 + 0) * 64 + vd) * 8);
        vp[1] = *(const half8_t*)(vn + ((vw * 2 + 1) * 64 + vd) * 8);
    }
    __syncthreads();

    for (int t = 0; t < kTilesHf; ++t) {
        const int cur = t & 1;
        const _Float16* Kb = Ksh[cur];
        const _Float16* Vb = Vsh[cur];
        _Float16* Kn = Ksh[cur ^ 1];
        _Float16* Vn = Vsh[cur ^ 1];

        // ---- MFMA front-load: QK(t) then PV(t-1), one contiguous 16-MFMA
        //      burst into the pipe right after the barrier. PV is register-
        //      only (pf/vfr carried); its result is needed earliest at the
        //      (rare) rescale below. Iter 0: pf/vfr are zeros -> O += 0. ----
        float16_t S0, S1;
        {
            half8_t kf0, kf1;
            kf0 = *(const half8_t*)(&Kb[(l31)      * kKStride + 0 * 16 + hi * 8]);
            kf1 = *(const half8_t*)(&Kb[(32 + l31) * kKStride + 0 * 16 + hi * 8]);
            __builtin_amdgcn_s_setprio(1);
            S0 = __builtin_amdgcn_mfma_f32_32x32x16_f16(kf0, qfrag[0], Zc, 0, 0, 0);
            S1 = __builtin_amdgcn_mfma_f32_32x32x16_f16(kf1, qfrag[0], Zc, 0, 0, 0);
#pragma unroll
            for (int kd = 1; kd < 4; ++kd) {
                kf0 = *(const half8_t*)(&Kb[(l31)      * kKStride + kd * 16 + hi * 8]);
                kf1 = *(const half8_t*)(&Kb[(32 + l31) * kKStride + kd * 16 + hi * 8]);
                S0 = __builtin_amdgcn_mfma_f32_32x32x16_f16(kf0, qfrag[kd], S0, 0, 0, 0);
                S1 = __builtin_amdgcn_mfma_f32_32x32x16_f16(kf1, qfrag[kd], S1, 0, 0, 0);
            }
#pragma unroll
            for (int kb = 0; kb < 4; ++kb)
                O[0] = __builtin_amdgcn_mfma_f32_32x32x16_f16(vfr0[kb], pf[kb], O[0], 0, 0, 0);
#pragma unroll
            for (int kb = 0; kb < 4; ++kb)
                O[1] = __builtin_amdgcn_mfma_f32_32x32x16_f16(vfr1[kb], pf[kb], O[1], 0, 0, 0);
            __builtin_amdgcn_s_setprio(0);
        }

        // ---- commit K/V(t+1) into other buffer (its readers synced at t-1
        //      end barrier); prefetch K/V(t+2) into regs (wraps, unused) ----
        *(half8_t*)(&Kn[koff0]) = kp[0];
        *(half8_t*)(&Kn[koff1]) = kp[1];
        *(half8_t*)(&Vn[voff0]) = vp[0];
        *(half8_t*)(&Vn[voff1]) = vp[1];
        {
            const int nt = (t + 2) & (kTilesHf - 1);
            const _Float16* kn = Kt + (size_t)nt * kTileH;
            const _Float16* vn = Vt + (size_t)nt * kTileH;
            kp[0] = *(const half8_t*)(kn + task0 * 8);
            kp[1] = *(const half8_t*)(kn + task1 * 8);
            vp[0] = *(const half8_t*)(vn + ((vw * 2 + 0) * 64 + vd) * 8);
            vp[1] = *(const half8_t*)(vn + ((vw * 2 + 1) * 64 + vd) * 8);
        }

        // ---- online softmax: max3 tree, ONE shfl_xor(32), lane-local l ----
        float v0 = f3(S0[0],  S0[1],  S0[2]);
        float v1 = f3(S0[3],  S0[4],  S0[5]);
        float v2 = f3(S0[6],  S0[7],  S0[8]);
        float v3 = f3(S0[9],  S0[10], S0[11]);
        float v4 = f3(S0[12], S0[13], S0[14]);
        float v5 = f3(S0[15], S1[0],  S1[1]);
        float v6 = f3(S1[2],  S1[3],  S1[4]);
        float v7 = f3(S1[5],  S1[6],  S1[7]);
        float v8 = f3(S1[8],  S1[9],  S1[10]);
        float v9 = f3(S1[11], S1[12], S1[13]);
        float w0 = f3(v0, v1, v2);
        float w1 = f3(v3, v4, v5);
        float w2 = f3(v6, v7, v8);
        float w3 = f3(v9, S1[14], S1[15]);
        float pm = fmaxf(fmaxf(w0, w1), fmaxf(w2, w3));
        pm = fmaxf(pm, __shfl_xor(pm, 32));

        // T13 defer-max. Rescale AFTER PV(t-1) was added: O holds tiles
        // tau<=t-1 at scale m_{t-1}; alpha brings it to m_t -> exact.
        const bool need = pm > m_run + 8.0f;
        if (__ballot(need)) {
            const float mn    = fmaxf(m_run, pm);
            const float alpha = __builtin_amdgcn_exp2f(m_run - mn);  // 1st iter: 0
            m_run = mn;
            l_run *= alpha;
#pragma unroll
            for (int r = 0; r < 16; ++r) { O[0][r] *= alpha; O[1][r] *= alpha; }
        }

        // ---- P = exp2(S - m) in place ----
#pragma unroll
        for (int r = 0; r < 16; ++r) {
            S0[r] = __builtin_amdgcn_exp2f(S0[r] - m_run);
            S1[r] = __builtin_amdgcn_exp2f(S1[r] - m_run);
        }

        // ---- pack pf(t) interleaved with vfr(t) LDS reads: S dies as vfr
        //      fills (peak VGPR ~122); l sum last covers vfr latency ----
        pf[0] = join8(cvt_pk4(S0[0],  S0[1],  S0[2],  S0[3]),
                      cvt_pk4(S0[4],  S0[5],  S0[6],  S0[7]));
        pf[1] = join8(cvt_pk4(S0[8],  S0[9],  S0[10], S0[11]),
                      cvt_pk4(S0[12], S0[13], S0[14], S0[15]));
#pragma unroll
        for (int kb = 0; kb < 4; ++kb)
            vfr0[kb] = *(const half8_t*)(&Vb[(l31) * kVStride + kb * 16 + hi * 8]);
        pf[2] = join8(cvt_pk4(S1[0],  S1[1],  S1[2],  S1[3]),
                      cvt_pk4(S1[4],  S1[5],  S1[6],  S1[7]));
        pf[3] = join8(cvt_pk4(S1[8],  S1[9],  S1[10], S1[11]),
                      cvt_pk4(S1[12], S1[13], S1[14], S1[15]));
#pragma unroll
        for (int kb = 0; kb < 4; ++kb)
            vfr1[kb] = *(const half8_t*)(&Vb[(32 + l31) * kVStride + kb * 16 + hi * 8]);
#define A4(v,a) ((v[a] + v[(a)+1]) + (v[(a)+2] + v[(a)+3]))
        l_run += ((A4(S0, 0) + A4(S0, 4)) + (A4(S0, 8) + A4(S0, 12)))
               + ((A4(S1, 0) + A4(S1, 4)) + (A4(S1, 8) + A4(S1, 12)));
#undef A4

        // single barrier per tile: kf/vfr reads of buf[cur] done;
        // commit to buf[cur^1] done
        __syncthreads();
    }

    // ---- epilogue: trailing PV(last) ----
    __builtin_amdgcn_s_setprio(1);
#pragma unroll
    for (int kb = 0; kb < 4; ++kb)
        O[0] = __builtin_amdgcn_mfma_f32_32x32x16_f16(vfr0[kb], pf[kb], O[0], 0, 0, 0);
#pragma unroll
    for (int kb = 0; kb < 4; ++kb)
        O[1] = __builtin_amdgcn_mfma_f32_32x32x16_f16(vfr1[kb], pf[kb], O[1], 0, 0, 0);
    __builtin_amdgcn_s_setprio(0);

    // ---- combine lane-pair l; O^T reg r -> d=(r&3)+8*(r>>2)+4*hi+32*dt ----
    l_run += __shfl_xor(l_run, 32);
    const float inv = 1.0f / l_run;
    const int   q   = q0 + l31;
    if (hf == 0) {
        float* op = Out + ((size_t)b * kL + q) * kD;
#pragma unroll
        for (int dt = 0; dt < 2; ++dt)
#pragma unroll
            for (int rr = 0; rr < 4; ++rr) {
                const int d0 = dt * 32 + rr * 8 + hi * 4;
                float4 w;
                w.x = O[dt][rr * 4 + 0] * inv;
                w.y = O[dt][rr * 4 + 1] * inv;
                w.z = O[dt][rr * 4 + 2] * inv;
                w.w = O[dt][rr * 4 + 3] * inv;
                *(float4*)(op + d0) = w;
            }
    } else {
        _Float16* op = O2ws + ((size_t)b * kL + q) * kD;
#pragma unroll
        for (int dt = 0; dt < 2; ++dt)
#pragma unroll
            for (int rr = 0; rr < 4; ++rr) {
                const int d0 = dt * 32 + rr * 8 + hi * 4;
                half4_t w = cvt_pk4(O[dt][rr * 4 + 0] * inv, O[dt][rr * 4 + 1] * inv,
                                    O[dt][rr * 4 + 2] * inv, O[dt][rr * 4 + 3] * inv);
                *(half4_t*)(op + d0) = w;
            }
    }
    if (hi == 0) {
        float2 ml; ml.x = m_run; ml.y = l_run;
        *(float2*)(Mlws + (((size_t)b * kL + q) * 2 + hf) * 2) = ml;
    }
}

// Merge the two key-halves: Out = w1*O1 + w2*O2, w_i = l_i*2^(m_i-m) / sum.
__global__ __launch_bounds__(256)
void combine(float* __restrict__ Out, const _Float16* __restrict__ O2ws,
             const float* __restrict__ Mlws)
{
    const int t   = threadIdx.x;
    const int row = blockIdx.x * 16 + (t >> 4);   // global row in [0, kB*kL)
    const int d0  = (t & 15) * 4;

    const float m1 = Mlws[(size_t)row * 4 + 0];
    const float l1 = Mlws[(size_t)row * 4 + 1];
    const float m2 = Mlws[(size_t)row * 4 + 2];
    const float l2 = Mlws[(size_t)row * 4 + 3];

    const float m  = fmaxf(m1, m2);
    float w1 = l1 * exp2f(m1 - m);
    float w2 = l2 * exp2f(m2 - m);
    const float inv = 1.0f / (w1 + w2);
    w1 *= inv; w2 *= inv;

    float* op = Out + (size_t)row * kD + d0;
    const _Float16* o2 = O2ws + (size_t)row * kD + d0;
    float4 a = *(const float4*)op;
    const half4_t h = *(const half4_t*)o2;
    a.x = a.x * w1 + (float)h[0] * w2;
    a.y = a.y * w1 + (float)h[1] * w2;
    a.z = a.z * w1 + (float)h[2] * w2;
    a.w = a.w * w1 + (float)h[3] * w2;
    *(float4*)op = a;
}

extern "C" void kernel_launch(void* const* d_in, const int* in_sizes, int n_in,
                              void* d_out, int out_size, void* d_ws, size_t ws_size,
                              hipStream_t stream) {
    const float* Q = (const float*)d_in[0];
    const float* K = (const float*)d_in[1];
    const float* V = (const float*)d_in[2];
    const float* s = (const float*)d_in[3];
    float* out = (float*)d_out;
    _Float16* Kws  = (_Float16*)d_ws;
    _Float16* Vws  = Kws + kWsHalves;
    _Float16* O2ws = Vws + kWsHalves;                 // 8.4 MB fp16 partial (half 1)
    float*    Mlws = (float*)(O2ws + kOHalves);       // [b*L][half][{m,l}] = 1.05 MB
    // total ws use: 16.8 + 8.4 + 1.05 = 26.2 MB  (>=34 MB proven in R5)

    prep_kv<<<dim3(2 * kB * kTiles), dim3(256), 0, stream>>>(K, V, Kws, Vws);
    fa_fwd<<<dim3(kL / kQTile, kB, kSplit), dim3(256), 0, stream>>>(Q, Kws, Vws, s, out, O2ws, Mlws);
    combine<<<dim3(kB * kL / 16), dim3(256), 0, stream>>>(out, O2ws, Mlws);
}

// Round 8
// 298.332 us; speedup vs baseline: 1.1317x; 1.1317x over previous
//
#include <hip/hip_runtime.h>
#include <hip/hip_fp16.h>

typedef _Float16 half2_t __attribute__((ext_vector_type(2)));
typedef _Float16 half4_t __attribute__((ext_vector_type(4)));
typedef _Float16 half8_t __attribute__((ext_vector_type(8)));
typedef float   float4_t __attribute__((ext_vector_type(4)));
typedef float  float16_t __attribute__((ext_vector_type(16)));

static __device__ __forceinline__ half2_t cvt_pk(float a, float b) {
    return __builtin_bit_cast(half2_t, __builtin_amdgcn_cvt_pkrtz(a, b));
}
static __device__ __forceinline__ half4_t cvt_pk4(float a, float b, float c, float d) {
    half2_t lo = cvt_pk(a, b), hi = cvt_pk(c, d);
    half4_t r;
    r[0] = lo[0]; r[1] = lo[1]; r[2] = hi[0]; r[3] = hi[1];
    return r;
}
static __device__ __forceinline__ half8_t cvt_pk8(const float4& a, const float4& b) {
    half4_t lo = cvt_pk4(a.x, a.y, a.z, a.w);
    half4_t hi = cvt_pk4(b.x, b.y, b.z, b.w);
    return __builtin_shufflevector(lo, hi, 0, 1, 2, 3, 4, 5, 6, 7);
}
static __device__ __forceinline__ half8_t join8(half4_t lo, half4_t hi) {
    return __builtin_shufflevector(lo, hi, 0, 1, 2, 3, 4, 5, 6, 7);
}
static __device__ __forceinline__ float f3(float a, float b, float c) {
    return fmaxf(fmaxf(a, b), c);   // clang fuses to v_max3_f32 (T17)
}

namespace {
constexpr int kB       = 16;    // batch
constexpr int kL       = 4096;  // Lq == Lk
constexpr int kD       = 64;    // head dim
constexpr int kQTile   = 128;   // 4 waves x 32 q-rows
constexpr int kBK      = 64;    // keys per tile
constexpr int kTiles   = kL / kBK;          // 64 key-tiles per batch
constexpr int kSplit   = 2;                 // K-split (grid 1024)
constexpr int kTilesHf = kTiles / kSplit;   // 32 key-tiles per half
constexpr int kTileH   = kBK * kD;          // 4096 halves per tile image
constexpr int kKStride = 72;    // Ksh stride (halves): b128 reads, even bank groups
constexpr int kVStride = 72;    // Vsh stride (halves): b128 reads/writes
constexpr int kQB      = kL / kQTile;       // 32 q-blocks per batch
constexpr size_t kWsHalves = (size_t)kB * kTiles * kTileH;  // 8 MB per operand
constexpr size_t kOHalves  = (size_t)kB * kL * kD;          // 8 MB fp16 partial O
}

// v19: fa inner loop reverted to v14 EXACTLY (97.4us; v15-v18 all regressed:
// L2-BW wall for V-direct, DMA bank contention for global_load_lds, VGPR
// spill for the carried pipeline). New lever: the stable ~84us of
// non-fa time. The combine kernel (~6us + ~10us graph-node overhead) is
// fused into fa's epilogue via a last-arriver protocol: both halves store
// partials exactly as before, then tid0 does threadfence (device-scope
// release) + atomicAdd on a per-(b,qblock) flag; the second arriver re-reads
// both partials and performs the identical blend. No spin -> no deadlock;
// flags zeroed per launch by a 2KB hipMemsetAsync (graph-capturable).

__global__ __launch_bounds__(256) void prep_kv(const float* __restrict__ K,
                                               const float* __restrict__ V,
                                               _Float16* __restrict__ Kws,
                                               _Float16* __restrict__ Vws)
{
    int blk = blockIdx.x;
    const int tid = threadIdx.x;
    if (blk < kB * kTiles) {
        // K image: fp16 row-major per tile, with key bits 2<->3 swapped so the
        // 32x32 MFMA S-reg order matches the PV B-operand key order.
        const float* src = K + (size_t)blk * kTileH;
        _Float16* dst = Kws + (size_t)blk * kTileH;
#pragma unroll
        for (int i = 0; i < 2; ++i) {
            const int task = tid + 256 * i;
            const int row  = task >> 3;       // dst physical row 0..63
            const int g    = task & 7;
            const int srow = (row & ~12) | ((row & 4) << 1) | ((row & 8) >> 1);
            const float* p = src + srow * kD + g * 8;
            const float4 a  = *(const float4*)p;
            const float4 b2 = *(const float4*)(p + 4);
            *(half8_t*)(dst + task * 8) = cvt_pk8(a, b2);
        }
    } else {
        // V^T image: [c8 chunk][d][8 keys] halves; natural key order
        blk -= kB * kTiles;
        const float* src = V + (size_t)blk * kTileH;   // [key][d]
        _Float16* dst = Vws + (size_t)blk * kTileH;
        const int d  = tid & 63;
        const int vw = tid >> 6;
#pragma unroll
        for (int i = 0; i < 2; ++i) {
            const int c8 = vw * 2 + i;
            const int k0 = c8 * 8;
            float p[8];
#pragma unroll
            for (int j = 0; j < 8; ++j) p[j] = src[(k0 + j) * kD + d];
            half4_t lo = cvt_pk4(p[0], p[1], p[2], p[3]);
            half4_t hi = cvt_pk4(p[4], p[5], p[6], p[7]);
            *(half8_t*)(dst + (c8 * 64 + d) * 8) = join8(lo, hi);
        }
    }
}

__global__ __launch_bounds__(256, 4)
void fa_fwd(const float* __restrict__ Q, const _Float16* __restrict__ Kws,
            const _Float16* __restrict__ Vws, const float* __restrict__ scale_ptr,
            float* __restrict__ Out, _Float16* __restrict__ O2ws,
            float* __restrict__ Mlws, int* __restrict__ Flags)
{
    __shared__ __align__(16) _Float16 Ksh[2][kBK * kKStride];  // [buf][key_phys][d]
    __shared__ __align__(16) _Float16 Vsh[2][kD * kVStride];   // [buf][d][key] (V^T)
    __shared__ int role;

    const int tid  = threadIdx.x;
    const int wave = tid >> 6;
    const int lane = tid & 63;
    const int l31  = lane & 31;   // q-row (QK B / PV B col); key row (QK A); d row (PV A)
    const int hi   = lane >> 5;   // half-select: k = hi*8 + j

    const int b  = blockIdx.y;
    const int hf = blockIdx.z;    // key-split half
    const int q0 = blockIdx.x * kQTile + wave * 32;

    // staging decompositions (match image layouts)
    const int task0 = tid, task1 = tid + 256;          // K: row=task>>3, g=task&7
    const int vd = tid & 63;                           // V: this thread's d
    const int vw = tid >> 6;                           // V: chunk pair base
    const int koff0 = (task0 >> 3) * kKStride + (task0 & 7) * 8;
    const int koff1 = (task1 >> 3) * kKStride + (task1 & 7) * 8;
    const int voff0 = vd * kVStride + (vw * 2 + 0) * 8;
    const int voff1 = vd * kVStride + (vw * 2 + 1) * 8;

    const float qscale = 1.4426950408889634f / scale_ptr[0];

    const float*    Qb = Q   + (size_t)b * kL * kD;
    const _Float16* Kt = Kws + ((size_t)b * kTiles + (size_t)hf * kTilesHf) * kTileH;
    const _Float16* Vt = Vws + ((size_t)b * kTiles + (size_t)hf * kTilesHf) * kTileH;

    // ---- Q fragments (B-operand 32x32x16: n=l31=qrow, k=hi*8+j, d=kd*16+k) ----
    half8_t qfrag[4];
    {
        const float* qrow = Qb + (size_t)(q0 + l31) * kD;
#pragma unroll
        for (int kd = 0; kd < 4; ++kd) {
            const float* p = qrow + kd * 16 + hi * 8;
            half8_t h;
#pragma unroll
            for (int j = 0; j < 8; ++j) h[j] = (_Float16)(p[j] * qscale);
            qfrag[kd] = h;
        }
    }

    // O^T accumulators: col=l31=q, row=d=(r&3)+8*(r>>2)+4*hi (+32*dt)
    float16_t O[2];
    O[0] = (float16_t)0.0f;
    O[1] = (float16_t)0.0f;
    float m_run = -__builtin_inff();
    float l_run = 0.0f;   // lane-local (this half's keys); pair-combined in epilogue
    const float16_t Zc = (float16_t)0.0f;

    // ---- prologue: stage tile 0 into buf0, prefetch tile 1 into regs ----
    half8_t kp[2], vp[2];
    kp[0] = *(const half8_t*)(Kt + task0 * 8);
    kp[1] = *(const half8_t*)(Kt + task1 * 8);
    vp[0] = *(const half8_t*)(Vt + ((vw * 2 + 0) * 64 + vd) * 8);
    vp[1] = *(const half8_t*)(Vt + ((vw * 2 + 1) * 64 + vd) * 8);
    *(half8_t*)(&Ksh[0][koff0]) = kp[0];
    *(half8_t*)(&Ksh[0][koff1]) = kp[1];
    *(half8_t*)(&Vsh[0][voff0]) = vp[0];
    *(half8_t*)(&Vsh[0][voff1]) = vp[1];
    {
        const _Float16* kn = Kt + (size_t)1 * kTileH;
        const _Float16* vn = Vt + (size_t)1 * kTileH;
        kp[0] = *(const half8_t*)(kn + task0 * 8);
        kp[1] = *(const half8_t*)(kn + task1 * 8);
        vp[0] = *(const half8_t*)(vn + ((vw * 2 + 0) * 64 + vd) * 8);
        vp[1] = *(const half8_t*)(vn + ((vw * 2 + 1) * 64 + vd) * 8);
    }
    __syncthreads();

    for (int t = 0; t < kTilesHf; ++t) {
        const int cur = t & 1;
        const _Float16* Kb = Ksh[cur];
        const _Float16* Vb = Vsh[cur];
        _Float16* Kn = Ksh[cur ^ 1];
        _Float16* Vn = Vsh[cur ^ 1];

        // ---- commit tile t+1 into the other buffer (overlaps with compute) ----
        *(half8_t*)(&Kn[koff0]) = kp[0];
        *(half8_t*)(&Kn[koff1]) = kp[1];
        *(half8_t*)(&Vn[voff0]) = vp[0];
        *(half8_t*)(&Vn[voff1]) = vp[1];

        // ---- issue global prefetch of tile t+2 (wraps; wrapped data unused) ----
        {
            const int nt = (t + 2) & (kTilesHf - 1);
            const _Float16* kn = Kt + (size_t)nt * kTileH;
            const _Float16* vn = Vt + (size_t)nt * kTileH;
            kp[0] = *(const half8_t*)(kn + task0 * 8);
            kp[1] = *(const half8_t*)(kn + task1 * 8);
            vp[0] = *(const half8_t*)(vn + ((vw * 2 + 0) * 64 + vd) * 8);
            vp[1] = *(const half8_t*)(vn + ((vw * 2 + 1) * 64 + vd) * 8);
        }

        // ---- S^T = K_phys * Q^T : 2 key-blocks x 4 d-chunks of 32x32x16 ----
        float16_t S0, S1;
        {
            half8_t kf0, kf1;
            kf0 = *(const half8_t*)(&Kb[(l31)      * kKStride + 0 * 16 + hi * 8]);
            kf1 = *(const half8_t*)(&Kb[(32 + l31) * kKStride + 0 * 16 + hi * 8]);
            __builtin_amdgcn_s_setprio(1);
            S0 = __builtin_amdgcn_mfma_f32_32x32x16_f16(kf0, qfrag[0], Zc, 0, 0, 0);
            S1 = __builtin_amdgcn_mfma_f32_32x32x16_f16(kf1, qfrag[0], Zc, 0, 0, 0);
#pragma unroll
            for (int kd = 1; kd < 4; ++kd) {
                kf0 = *(const half8_t*)(&Kb[(l31)      * kKStride + kd * 16 + hi * 8]);
                kf1 = *(const half8_t*)(&Kb[(32 + l31) * kKStride + kd * 16 + hi * 8]);
                S0 = __builtin_amdgcn_mfma_f32_32x32x16_f16(kf0, qfrag[kd], S0, 0, 0, 0);
                S1 = __builtin_amdgcn_mfma_f32_32x32x16_f16(kf1, qfrag[kd], S1, 0, 0, 0);
            }
            __builtin_amdgcn_s_setprio(0);
        }

        // ---- online softmax: max3 tree, ONE shfl_xor(32), lane-local l ----
        float v0 = f3(S0[0],  S0[1],  S0[2]);
        float v1 = f3(S0[3],  S0[4],  S0[5]);
        float v2 = f3(S0[6],  S0[7],  S0[8]);
        float v3 = f3(S0[9],  S0[10], S0[11]);
        float v4 = f3(S0[12], S0[13], S0[14]);
        float v5 = f3(S0[15], S1[0],  S1[1]);
        float v6 = f3(S1[2],  S1[3],  S1[4]);
        float v7 = f3(S1[5],  S1[6],  S1[7]);
        float v8 = f3(S1[8],  S1[9],  S1[10]);
        float v9 = f3(S1[11], S1[12], S1[13]);
        float w0 = f3(v0, v1, v2);
        float w1 = f3(v3, v4, v5);
        float w2 = f3(v6, v7, v8);
        float w3 = f3(v9, S1[14], S1[15]);
        float pm = fmaxf(fmaxf(w0, w1), fmaxf(w2, w3));
        pm = fmaxf(pm, __shfl_xor(pm, 32));

        // T13 defer-max: skip rescale while growth <= 8 (P bounded by 2^8, exact)
        const bool need = pm > m_run + 8.0f;
        if (__ballot(need)) {
            const float mn    = fmaxf(m_run, pm);
            const float alpha = __builtin_amdgcn_exp2f(m_run - mn);  // 1st iter: 0
            m_run = mn;
            l_run *= alpha;
#pragma unroll
            for (int r = 0; r < 16; ++r) { O[0][r] *= alpha; O[1][r] *= alpha; }
        }

        // ---- P = exp2(S - m) in place; pack B-fragments; local l sum ----
#pragma unroll
        for (int r = 0; r < 16; ++r) {
            S0[r] = __builtin_amdgcn_exp2f(S0[r] - m_run);
            S1[r] = __builtin_amdgcn_exp2f(S1[r] - m_run);
        }
        half8_t pf[4];
        pf[0] = join8(cvt_pk4(S0[0],  S0[1],  S0[2],  S0[3]),
                      cvt_pk4(S0[4],  S0[5],  S0[6],  S0[7]));
        pf[1] = join8(cvt_pk4(S0[8],  S0[9],  S0[10], S0[11]),
                      cvt_pk4(S0[12], S0[13], S0[14], S0[15]));
        pf[2] = join8(cvt_pk4(S1[0],  S1[1],  S1[2],  S1[3]),
                      cvt_pk4(S1[4],  S1[5],  S1[6],  S1[7]));
        pf[3] = join8(cvt_pk4(S1[8],  S1[9],  S1[10], S1[11]),
                      cvt_pk4(S1[12], S1[13], S1[14], S1[15]));
#define A4(v,a) ((v[a] + v[(a)+1]) + (v[(a)+2] + v[(a)+3]))
        l_run += ((A4(S0, 0) + A4(S0, 4)) + (A4(S0, 8) + A4(S0, 12)))
               + ((A4(S1, 0) + A4(S1, 4)) + (A4(S1, 8) + A4(S1, 12)));
#undef A4

        // ---- O^T += V^T * P : 4 key16-blocks x 2 d-blocks, full-rate x32x16 ----
        __builtin_amdgcn_s_setprio(1);
#pragma unroll
        for (int kb = 0; kb < 4; ++kb) {
            const half8_t vf0 = *(const half8_t*)(
                &Vb[(l31)      * kVStride + kb * 16 + hi * 8]);
            const half8_t vf1 = *(const half8_t*)(
                &Vb[(32 + l31) * kVStride + kb * 16 + hi * 8]);
            O[0] = __builtin_amdgcn_mfma_f32_32x32x16_f16(vf0, pf[kb], O[0], 0, 0, 0);
            O[1] = __builtin_amdgcn_mfma_f32_32x32x16_f16(vf1, pf[kb], O[1], 0, 0, 0);
        }
        __builtin_amdgcn_s_setprio(0);

        // single barrier per tile: reads of buf[cur] done; writes to buf[cur^1] done
        __syncthreads();
    }

    // ---- epilogue: combine lane-pair l; O^T reg r -> d=(r&3)+8*(r>>2)+4*hi+32*dt ----
    l_run += __shfl_xor(l_run, 32);
    const float inv = 1.0f / l_run;
    const int   q   = q0 + l31;
    if (hf == 0) {
        float* op = Out + ((size_t)b * kL + q) * kD;
#pragma unroll
        for (int dt = 0; dt < 2; ++dt)
#pragma unroll
            for (int rr = 0; rr < 4; ++rr) {
                const int d0 = dt * 32 + rr * 8 + hi * 4;
                float4 w;
                w.x = O[dt][rr * 4 + 0] * inv;
                w.y = O[dt][rr * 4 + 1] * inv;
                w.z = O[dt][rr * 4 + 2] * inv;
                w.w = O[dt][rr * 4 + 3] * inv;
                *(float4*)(op + d0) = w;
            }
    } else {
        _Float16* op = O2ws + ((size_t)b * kL + q) * kD;
#pragma unroll
        for (int dt = 0; dt < 2; ++dt)
#pragma unroll
            for (int rr = 0; rr < 4; ++rr) {
                const int d0 = dt * 32 + rr * 8 + hi * 4;
                half4_t w = cvt_pk4(O[dt][rr * 4 + 0] * inv, O[dt][rr * 4 + 1] * inv,
                                    O[dt][rr * 4 + 2] * inv, O[dt][rr * 4 + 3] * inv);
                *(half4_t*)(op + d0) = w;
            }
    }
    if (hi == 0) {
        float2 ml; ml.x = m_run; ml.y = l_run;
        *(float2*)(Mlws + (((size_t)b * kL + q) * 2 + hf) * 2) = ml;
    }

    // ---- fused split-K merge: last-arriver protocol (replaces combine) ----
    __syncthreads();   // all partial stores issued & drained (vmcnt(0) at barrier)
    if (tid == 0) {
        __threadfence();                       // device-scope release of our stores
        role = atomicAdd(&Flags[b * kQB + blockIdx.x], 1);
    }
    __syncthreads();
    if (role == 1) {                           // exactly one block per pair merges
        __threadfence();                       // acquire: other half's stores visible
        const int r  = tid >> 1;               // 0..127: row within this q-block
        const int dh = (tid & 1) * 32;         // half of the d-dimension
        const size_t rowg = (size_t)b * kL + blockIdx.x * kQTile + r;
        const float m1 = Mlws[rowg * 4 + 0];
        const float l1 = Mlws[rowg * 4 + 1];
        const float m2 = Mlws[rowg * 4 + 2];
        const float l2 = Mlws[rowg * 4 + 3];
        const float mm = fmaxf(m1, m2);
        float w1 = l1 * __builtin_amdgcn_exp2f(m1 - mm);
        float w2 = l2 * __builtin_amdgcn_exp2f(m2 - mm);
        const float winv = 1.0f / (w1 + w2);
        w1 *= winv; w2 *= winv;
        float* op = Out + rowg * kD + dh;
        const _Float16* o2 = O2ws + rowg * kD + dh;
#pragma unroll
        for (int j = 0; j < 8; ++j) {
            float4 a = *(const float4*)(op + j * 4);
            const half4_t h = *(const half4_t*)(o2 + j * 4);
            a.x = a.x * w1 + (float)h[0] * w2;
            a.y = a.y * w1 + (float)h[1] * w2;
            a.z = a.z * w1 + (float)h[2] * w2;
            a.w = a.w * w1 + (float)h[3] * w2;
            *(float4*)(op + j * 4) = a;
        }
    }
}

extern "C" void kernel_launch(void* const* d_in, const int* in_sizes, int n_in,
                              void* d_out, int out_size, void* d_ws, size_t ws_size,
                              hipStream_t stream) {
    const float* Q = (const float*)d_in[0];
    const float* K = (const float*)d_in[1];
    const float* V = (const float*)d_in[2];
    const float* s = (const float*)d_in[3];
    float* out = (float*)d_out;
    _Float16* Kws  = (_Float16*)d_ws;
    _Float16* Vws  = Kws + kWsHalves;
    _Float16* O2ws = Vws + kWsHalves;                 // 8.4 MB fp16 partial (half 1)
    float*    Mlws = (float*)(O2ws + kOHalves);       // [b*L][half][{m,l}] = 1.05 MB
    int*      Flags = (int*)(Mlws + (size_t)kB * kL * 4);  // 512 ints, zeroed per launch
    // total ws use: 16.8 + 8.4 + 1.05 + ~0 = 26.2 MB  (>=34 MB proven in R5)

    hipMemsetAsync(Flags, 0, kB * kQB * sizeof(int), stream);
    prep_kv<<<dim3(2 * kB * kTiles), dim3(256), 0, stream>>>(K, V, Kws, Vws);
    fa_fwd<<<dim3(kQB, kB, kSplit), dim3(256), 0, stream>>>(Q, Kws, Vws, s, out, O2ws, Mlws, Flags);
}

// Round 9
// 192.245 us; speedup vs baseline: 1.7562x; 1.5518x over previous
//
#include <hip/hip_runtime.h>
#include <hip/hip_fp16.h>

typedef _Float16 half2_t __attribute__((ext_vector_type(2)));
typedef _Float16 half4_t __attribute__((ext_vector_type(4)));
typedef _Float16 half8_t __attribute__((ext_vector_type(8)));
typedef float   float4_t __attribute__((ext_vector_type(4)));
typedef float  float16_t __attribute__((ext_vector_type(16)));

static __device__ __forceinline__ half2_t cvt_pk(float a, float b) {
    return __builtin_bit_cast(half2_t, __builtin_amdgcn_cvt_pkrtz(a, b));
}
static __device__ __forceinline__ half4_t cvt_pk4(float a, float b, float c, float d) {
    half2_t lo = cvt_pk(a, b), hi = cvt_pk(c, d);
    half4_t r;
    r[0] = lo[0]; r[1] = lo[1]; r[2] = hi[0]; r[3] = hi[1];
    return r;
}
static __device__ __forceinline__ half8_t cvt_pk8(const float4& a, const float4& b) {
    half4_t lo = cvt_pk4(a.x, a.y, a.z, a.w);
    half4_t hi = cvt_pk4(b.x, b.y, b.z, b.w);
    return __builtin_shufflevector(lo, hi, 0, 1, 2, 3, 4, 5, 6, 7);
}
static __device__ __forceinline__ half8_t join8(half4_t lo, half4_t hi) {
    return __builtin_shufflevector(lo, hi, 0, 1, 2, 3, 4, 5, 6, 7);
}
static __device__ __forceinline__ float f3(float a, float b, float c) {
    return fmaxf(fmaxf(a, b), c);   // clang fuses to v_max3_f32 (T17)
}

namespace {
constexpr int kB       = 16;    // batch
constexpr int kL       = 4096;  // Lq == Lk
constexpr int kD       = 64;    // head dim
constexpr int kQTile   = 128;   // 4 waves x 32 q-rows
constexpr int kBK      = 64;    // keys per tile
constexpr int kTiles   = kL / kBK;          // 64 key-tiles per batch
constexpr int kSplit   = 2;                 // K-split (grid 1024)
constexpr int kTilesHf = kTiles / kSplit;   // 32 key-tiles per half
constexpr int kTileH   = kBK * kD;          // 4096 halves per tile image
constexpr int kKStride = 72;    // Ksh stride (halves): b128 reads, even bank groups
constexpr int kVStride = 72;    // Vsh stride (halves): b128 reads/writes
constexpr size_t kWsHalves = (size_t)kB * kTiles * kTileH;  // 8 MB per operand
constexpr size_t kOHalves  = (size_t)kB * kL * kD;          // 8 MB fp16 partial O
}

// v20: full revert to v14 (R3, 186.0us total / fa 97.4us — verified optimum).
// v15-v19 post-mortems closed every fa restructure family:
//   v15/v17 V-in-reg: VGPR spill / L2-BW wall (LDS staging is a required
//     bandwidth amplifier; 40KB/block-tile direct = 87B/cy/CU > ~56 ceiling)
//   v16 global_load_lds: DMA-vs-read bank contention + barrier vmcnt(0) drain
//   v18 carried pipeline: VGPR spill (FETCH/WRITE blow-up)
//   v19 fused merge: per-block device-scope fences = per-XCD L2
//     writeback/TCC-drain storm (G16: kernel-boundary coherence is cheaper)
// Only off-loop change vs R3: combine at 2048 blocks x 8 floats/thread
// (was 4096 x 4) — same math, same traffic, half the launch/tail cost.

__global__ __launch_bounds__(256) void prep_kv(const float* __restrict__ K,
                                               const float* __restrict__ V,
                                               _Float16* __restrict__ Kws,
                                               _Float16* __restrict__ Vws)
{
    int blk = blockIdx.x;
    const int tid = threadIdx.x;
    if (blk < kB * kTiles) {
        // K image: fp16 row-major per tile, with key bits 2<->3 swapped so the
        // 32x32 MFMA S-reg order matches the PV B-operand key order.
        const float* src = K + (size_t)blk * kTileH;
        _Float16* dst = Kws + (size_t)blk * kTileH;
#pragma unroll
        for (int i = 0; i < 2; ++i) {
            const int task = tid + 256 * i;
            const int row  = task >> 3;       // dst physical row 0..63
            const int g    = task & 7;
            const int srow = (row & ~12) | ((row & 4) << 1) | ((row & 8) >> 1);
            const float* p = src + srow * kD + g * 8;
            const float4 a  = *(const float4*)p;
            const float4 b2 = *(const float4*)(p + 4);
            *(half8_t*)(dst + task * 8) = cvt_pk8(a, b2);
        }
    } else {
        // V^T image: [c8 chunk][d][8 keys] halves; natural key order
        blk -= kB * kTiles;
        const float* src = V + (size_t)blk * kTileH;   // [key][d]
        _Float16* dst = Vws + (size_t)blk * kTileH;
        const int d  = tid & 63;
        const int vw = tid >> 6;
#pragma unroll
        for (int i = 0; i < 2; ++i) {
            const int c8 = vw * 2 + i;
            const int k0 = c8 * 8;
            float p[8];
#pragma unroll
            for (int j = 0; j < 8; ++j) p[j] = src[(k0 + j) * kD + d];
            half4_t lo = cvt_pk4(p[0], p[1], p[2], p[3]);
            half4_t hi = cvt_pk4(p[4], p[5], p[6], p[7]);
            *(half8_t*)(dst + (c8 * 64 + d) * 8) = join8(lo, hi);
        }
    }
}

__global__ __launch_bounds__(256, 4)
void fa_fwd(const float* __restrict__ Q, const _Float16* __restrict__ Kws,
            const _Float16* __restrict__ Vws, const float* __restrict__ scale_ptr,
            float* __restrict__ Out, _Float16* __restrict__ O2ws,
            float* __restrict__ Mlws)
{
    __shared__ __align__(16) _Float16 Ksh[2][kBK * kKStride];  // [buf][key_phys][d]
    __shared__ __align__(16) _Float16 Vsh[2][kD * kVStride];   // [buf][d][key] (V^T)

    const int tid  = threadIdx.x;
    const int wave = tid >> 6;
    const int lane = tid & 63;
    const int l31  = lane & 31;   // q-row (QK B / PV B col); key row (QK A); d row (PV A)
    const int hi   = lane >> 5;   // half-select: k = hi*8 + j

    const int b  = blockIdx.y;
    const int hf = blockIdx.z;    // key-split half
    const int q0 = blockIdx.x * kQTile + wave * 32;

    // staging decompositions (match image layouts)
    const int task0 = tid, task1 = tid + 256;          // K: row=task>>3, g=task&7
    const int vd = tid & 63;                           // V: this thread's d
    const int vw = tid >> 6;                           // V: chunk pair base
    const int koff0 = (task0 >> 3) * kKStride + (task0 & 7) * 8;
    const int koff1 = (task1 >> 3) * kKStride + (task1 & 7) * 8;
    const int voff0 = vd * kVStride + (vw * 2 + 0) * 8;
    const int voff1 = vd * kVStride + (vw * 2 + 1) * 8;

    const float qscale = 1.4426950408889634f / scale_ptr[0];

    const float*    Qb = Q   + (size_t)b * kL * kD;
    const _Float16* Kt = Kws + ((size_t)b * kTiles + (size_t)hf * kTilesHf) * kTileH;
    const _Float16* Vt = Vws + ((size_t)b * kTiles + (size_t)hf * kTilesHf) * kTileH;

    // ---- Q fragments (B-operand 32x32x16: n=l31=qrow, k=hi*8+j, d=kd*16+k) ----
    half8_t qfrag[4];
    {
        const float* qrow = Qb + (size_t)(q0 + l31) * kD;
#pragma unroll
        for (int kd = 0; kd < 4; ++kd) {
            const float* p = qrow + kd * 16 + hi * 8;
            half8_t h;
#pragma unroll
            for (int j = 0; j < 8; ++j) h[j] = (_Float16)(p[j] * qscale);
            qfrag[kd] = h;
        }
    }

    // O^T accumulators: col=l31=q, row=d=(r&3)+8*(r>>2)+4*hi (+32*dt)
    float16_t O[2];
    O[0] = (float16_t)0.0f;
    O[1] = (float16_t)0.0f;
    float m_run = -__builtin_inff();
    float l_run = 0.0f;   // lane-local (this half's keys); pair-combined in epilogue
    const float16_t Zc = (float16_t)0.0f;

    // ---- prologue: stage tile 0 into buf0, prefetch tile 1 into regs ----
    half8_t kp[2], vp[2];
    kp[0] = *(const half8_t*)(Kt + task0 * 8);
    kp[1] = *(const half8_t*)(Kt + task1 * 8);
    vp[0] = *(const half8_t*)(Vt + ((vw * 2 + 0) * 64 + vd) * 8);
    vp[1] = *(const half8_t*)(Vt + ((vw * 2 + 1) * 64 + vd) * 8);
    *(half8_t*)(&Ksh[0][koff0]) = kp[0];
    *(half8_t*)(&Ksh[0][koff1]) = kp[1];
    *(half8_t*)(&Vsh[0][voff0]) = vp[0];
    *(half8_t*)(&Vsh[0][voff1]) = vp[1];
    {
        const _Float16* kn = Kt + (size_t)1 * kTileH;
        const _Float16* vn = Vt + (size_t)1 * kTileH;
        kp[0] = *(const half8_t*)(kn + task0 * 8);
        kp[1] = *(const half8_t*)(kn + task1 * 8);
        vp[0] = *(const half8_t*)(vn + ((vw * 2 + 0) * 64 + vd) * 8);
        vp[1] = *(const half8_t*)(vn + ((vw * 2 + 1) * 64 + vd) * 8);
    }
    __syncthreads();

    for (int t = 0; t < kTilesHf; ++t) {
        const int cur = t & 1;
        const _Float16* Kb = Ksh[cur];
        const _Float16* Vb = Vsh[cur];
        _Float16* Kn = Ksh[cur ^ 1];
        _Float16* Vn = Vsh[cur ^ 1];

        // ---- commit tile t+1 into the other buffer (overlaps with compute) ----
        *(half8_t*)(&Kn[koff0]) = kp[0];
        *(half8_t*)(&Kn[koff1]) = kp[1];
        *(half8_t*)(&Vn[voff0]) = vp[0];
        *(half8_t*)(&Vn[voff1]) = vp[1];

        // ---- issue global prefetch of tile t+2 (wraps; wrapped data unused) ----
        {
            const int nt = (t + 2) & (kTilesHf - 1);
            const _Float16* kn = Kt + (size_t)nt * kTileH;
            const _Float16* vn = Vt + (size_t)nt * kTileH;
            kp[0] = *(const half8_t*)(kn + task0 * 8);
            kp[1] = *(const half8_t*)(kn + task1 * 8);
            vp[0] = *(const half8_t*)(vn + ((vw * 2 + 0) * 64 + vd) * 8);
            vp[1] = *(const half8_t*)(vn + ((vw * 2 + 1) * 64 + vd) * 8);
        }

        // ---- S^T = K_phys * Q^T : 2 key-blocks x 4 d-chunks of 32x32x16 ----
        float16_t S0, S1;
        {
            half8_t kf0, kf1;
            kf0 = *(const half8_t*)(&Kb[(l31)      * kKStride + 0 * 16 + hi * 8]);
            kf1 = *(const half8_t*)(&Kb[(32 + l31) * kKStride + 0 * 16 + hi * 8]);
            __builtin_amdgcn_s_setprio(1);
            S0 = __builtin_amdgcn_mfma_f32_32x32x16_f16(kf0, qfrag[0], Zc, 0, 0, 0);
            S1 = __builtin_amdgcn_mfma_f32_32x32x16_f16(kf1, qfrag[0], Zc, 0, 0, 0);
#pragma unroll
            for (int kd = 1; kd < 4; ++kd) {
                kf0 = *(const half8_t*)(&Kb[(l31)      * kKStride + kd * 16 + hi * 8]);
                kf1 = *(const half8_t*)(&Kb[(32 + l31) * kKStride + kd * 16 + hi * 8]);
                S0 = __builtin_amdgcn_mfma_f32_32x32x16_f16(kf0, qfrag[kd], S0, 0, 0, 0);
                S1 = __builtin_amdgcn_mfma_f32_32x32x16_f16(kf1, qfrag[kd], S1, 0, 0, 0);
            }
            __builtin_amdgcn_s_setprio(0);
        }

        // ---- online softmax: max3 tree, ONE shfl_xor(32), lane-local l ----
        float v0 = f3(S0[0],  S0[1],  S0[2]);
        float v1 = f3(S0[3],  S0[4],  S0[5]);
        float v2 = f3(S0[6],  S0[7],  S0[8]);
        float v3 = f3(S0[9],  S0[10], S0[11]);
        float v4 = f3(S0[12], S0[13], S0[14]);
        float v5 = f3(S0[15], S1[0],  S1[1]);
        float v6 = f3(S1[2],  S1[3],  S1[4]);
        float v7 = f3(S1[5],  S1[6],  S1[7]);
        float v8 = f3(S1[8],  S1[9],  S1[10]);
        float v9 = f3(S1[11], S1[12], S1[13]);
        float w0 = f3(v0, v1, v2);
        float w1 = f3(v3, v4, v5);
        float w2 = f3(v6, v7, v8);
        float w3 = f3(v9, S1[14], S1[15]);
        float pm = fmaxf(fmaxf(w0, w1), fmaxf(w2, w3));
        pm = fmaxf(pm, __shfl_xor(pm, 32));

        // T13 defer-max: skip rescale while growth <= 8 (P bounded by 2^8, exact)
        const bool need = pm > m_run + 8.0f;
        if (__ballot(need)) {
            const float mn    = fmaxf(m_run, pm);
            const float alpha = __builtin_amdgcn_exp2f(m_run - mn);  // 1st iter: 0
            m_run = mn;
            l_run *= alpha;
#pragma unroll
            for (int r = 0; r < 16; ++r) { O[0][r] *= alpha; O[1][r] *= alpha; }
        }

        // ---- P = exp2(S - m) in place; pack B-fragments; local l sum ----
#pragma unroll
        for (int r = 0; r < 16; ++r) {
            S0[r] = __builtin_amdgcn_exp2f(S0[r] - m_run);
            S1[r] = __builtin_amdgcn_exp2f(S1[r] - m_run);
        }
        half8_t pf[4];
        pf[0] = join8(cvt_pk4(S0[0],  S0[1],  S0[2],  S0[3]),
                      cvt_pk4(S0[4],  S0[5],  S0[6],  S0[7]));
        pf[1] = join8(cvt_pk4(S0[8],  S0[9],  S0[10], S0[11]),
                      cvt_pk4(S0[12], S0[13], S0[14], S0[15]));
        pf[2] = join8(cvt_pk4(S1[0],  S1[1],  S1[2],  S1[3]),
                      cvt_pk4(S1[4],  S1[5],  S1[6],  S1[7]));
        pf[3] = join8(cvt_pk4(S1[8],  S1[9],  S1[10], S1[11]),
                      cvt_pk4(S1[12], S1[13], S1[14], S1[15]));
#define A4(v,a) ((v[a] + v[(a)+1]) + (v[(a)+2] + v[(a)+3]))
        l_run += ((A4(S0, 0) + A4(S0, 4)) + (A4(S0, 8) + A4(S0, 12)))
               + ((A4(S1, 0) + A4(S1, 4)) + (A4(S1, 8) + A4(S1, 12)));
#undef A4

        // ---- O^T += V^T * P : 4 key16-blocks x 2 d-blocks, full-rate x32x16 ----
        __builtin_amdgcn_s_setprio(1);
#pragma unroll
        for (int kb = 0; kb < 4; ++kb) {
            const half8_t vf0 = *(const half8_t*)(
                &Vb[(l31)      * kVStride + kb * 16 + hi * 8]);
            const half8_t vf1 = *(const half8_t*)(
                &Vb[(32 + l31) * kVStride + kb * 16 + hi * 8]);
            O[0] = __builtin_amdgcn_mfma_f32_32x32x16_f16(vf0, pf[kb], O[0], 0, 0, 0);
            O[1] = __builtin_amdgcn_mfma_f32_32x32x16_f16(vf1, pf[kb], O[1], 0, 0, 0);
        }
        __builtin_amdgcn_s_setprio(0);

        // single barrier per tile: reads of buf[cur] done; writes to buf[cur^1] done
        __syncthreads();
    }

    // ---- epilogue: combine lane-pair l; O^T reg r -> d=(r&3)+8*(r>>2)+4*hi+32*dt ----
    l_run += __shfl_xor(l_run, 32);
    const float inv = 1.0f / l_run;
    const int   q   = q0 + l31;
    if (hf == 0) {
        float* op = Out + ((size_t)b * kL + q) * kD;
#pragma unroll
        for (int dt = 0; dt < 2; ++dt)
#pragma unroll
            for (int rr = 0; rr < 4; ++rr) {
                const int d0 = dt * 32 + rr * 8 + hi * 4;
                float4 w;
                w.x = O[dt][rr * 4 + 0] * inv;
                w.y = O[dt][rr * 4 + 1] * inv;
                w.z = O[dt][rr * 4 + 2] * inv;
                w.w = O[dt][rr * 4 + 3] * inv;
                *(float4*)(op + d0) = w;
            }
    } else {
        _Float16* op = O2ws + ((size_t)b * kL + q) * kD;
#pragma unroll
        for (int dt = 0; dt < 2; ++dt)
#pragma unroll
            for (int rr = 0; rr < 4; ++rr) {
                const int d0 = dt * 32 + rr * 8 + hi * 4;
                half4_t w = cvt_pk4(O[dt][rr * 4 + 0] * inv, O[dt][rr * 4 + 1] * inv,
                                    O[dt][rr * 4 + 2] * inv, O[dt][rr * 4 + 3] * inv);
                *(half4_t*)(op + d0) = w;
            }
    }
    if (hi == 0) {
        float2 ml; ml.x = m_run; ml.y = l_run;
        *(float2*)(Mlws + (((size_t)b * kL + q) * 2 + hf) * 2) = ml;
    }
}

// Merge the two key-halves: Out = w1*O1 + w2*O2, w_i = l_i*2^(m_i-m) / sum.
// 2048 blocks x 256 thr, 8 floats/thread (256B-contiguous per 8-lane group).
__global__ __launch_bounds__(256)
void combine(float* __restrict__ Out, const _Float16* __restrict__ O2ws,
             const float* __restrict__ Mlws)
{
    const int t   = threadIdx.x;
    const int row = blockIdx.x * 32 + (t >> 3);   // global row in [0, kB*kL)
    const int d0  = (t & 7) * 8;

    const float m1 = Mlws[(size_t)row * 4 + 0];
    const float l1 = Mlws[(size_t)row * 4 + 1];
    const float m2 = Mlws[(size_t)row * 4 + 2];
    const float l2 = Mlws[(size_t)row * 4 + 3];

    const float m  = fmaxf(m1, m2);
    float w1 = l1 * exp2f(m1 - m);
    float w2 = l2 * exp2f(m2 - m);
    const float inv = 1.0f / (w1 + w2);
    w1 *= inv; w2 *= inv;

    float* op = Out + (size_t)row * kD + d0;
    const _Float16* o2 = O2ws + (size_t)row * kD + d0;
    const half8_t h = *(const half8_t*)o2;
    float4 a = *(const float4*)op;
    float4 c = *(const float4*)(op + 4);
    a.x = a.x * w1 + (float)h[0] * w2;
    a.y = a.y * w1 + (float)h[1] * w2;
    a.z = a.z * w1 + (float)h[2] * w2;
    a.w = a.w * w1 + (float)h[3] * w2;
    c.x = c.x * w1 + (float)h[4] * w2;
    c.y = c.y * w1 + (float)h[5] * w2;
    c.z = c.z * w1 + (float)h[6] * w2;
    c.w = c.w * w1 + (float)h[7] * w2;
    *(float4*)op = a;
    *(float4*)(op + 4) = c;
}

extern "C" void kernel_launch(void* const* d_in, const int* in_sizes, int n_in,
                              void* d_out, int out_size, void* d_ws, size_t ws_size,
                              hipStream_t stream) {
    const float* Q = (const float*)d_in[0];
    const float* K = (const float*)d_in[1];
    const float* V = (const float*)d_in[2];
    const float* s = (const float*)d_in[3];
    float* out = (float*)d_out;
    _Float16* Kws  = (_Float16*)d_ws;
    _Float16* Vws  = Kws + kWsHalves;
    _Float16* O2ws = Vws + kWsHalves;                 // 8.4 MB fp16 partial (half 1)
    float*    Mlws = (float*)(O2ws + kOHalves);       // [b*L][half][{m,l}] = 1.05 MB
    // total ws use: 16.8 + 8.4 + 1.05 = 26.2 MB  (>=34 MB proven in R5)

    prep_kv<<<dim3(2 * kB * kTiles), dim3(256), 0, stream>>>(K, V, Kws, Vws);
    fa_fwd<<<dim3(kL / kQTile, kB, kSplit), dim3(256), 0, stream>>>(Q, Kws, Vws, s, out, O2ws, Mlws);
    combine<<<dim3(kB * kL / 32), dim3(256), 0, stream>>>(out, O2ws, Mlws);
}

// Round 10
// 188.908 us; speedup vs baseline: 1.7872x; 1.0177x over previous
//
#include <hip/hip_runtime.h>
#include <hip/hip_fp16.h>

typedef _Float16 half2_t __attribute__((ext_vector_type(2)));
typedef _Float16 half4_t __attribute__((ext_vector_type(4)));
typedef _Float16 half8_t __attribute__((ext_vector_type(8)));
typedef float   float4_t __attribute__((ext_vector_type(4)));
typedef float  float16_t __attribute__((ext_vector_type(16)));

static __device__ __forceinline__ half2_t cvt_pk(float a, float b) {
    return __builtin_bit_cast(half2_t, __builtin_amdgcn_cvt_pkrtz(a, b));
}
static __device__ __forceinline__ half4_t cvt_pk4(float a, float b, float c, float d) {
    half2_t lo = cvt_pk(a, b), hi = cvt_pk(c, d);
    half4_t r;
    r[0] = lo[0]; r[1] = lo[1]; r[2] = hi[0]; r[3] = hi[1];
    return r;
}
static __device__ __forceinline__ half8_t cvt_pk8(const float4& a, const float4& b) {
    half4_t lo = cvt_pk4(a.x, a.y, a.z, a.w);
    half4_t hi = cvt_pk4(b.x, b.y, b.z, b.w);
    return __builtin_shufflevector(lo, hi, 0, 1, 2, 3, 4, 5, 6, 7);
}
static __device__ __forceinline__ half8_t join8(half4_t lo, half4_t hi) {
    return __builtin_shufflevector(lo, hi, 0, 1, 2, 3, 4, 5, 6, 7);
}
static __device__ __forceinline__ float f3(float a, float b, float c) {
    return fmaxf(fmaxf(a, b), c);   // clang fuses to v_max3_f32 (T17)
}

namespace {
constexpr int kB       = 16;    // batch
constexpr int kL       = 4096;  // Lq == Lk
constexpr int kD       = 64;    // head dim
constexpr int kQTile   = 128;   // 4 waves x 32 q-rows
constexpr int kBK      = 64;    // keys per tile
constexpr int kTiles   = kL / kBK;          // 64 key-tiles per batch
constexpr int kSplit   = 2;                 // K-split (grid 1024)
constexpr int kTilesHf = kTiles / kSplit;   // 32 key-tiles per half
constexpr int kTileH   = kBK * kD;          // 4096 halves per tile image
constexpr int kKStride = 72;    // Ksh stride (halves): b128 reads, even bank groups
constexpr int kVStride = 72;    // Vsh stride (halves): b128 reads/writes
constexpr size_t kWsHalves = (size_t)kB * kTiles * kTileH;  // 8 MB per operand
constexpr size_t kOHalves  = (size_t)kB * kL * kD;          // 8 MB fp16 partial O
}

// v21: v20 (= verified-optimal v14 inner loop) + T1 XCD-aware block swizzle
// in fa_fwd ONLY. Rationale: grid 1024 fully resident (4 blocks/CU); default
// linearization (qblock fastest, XCD = wgid%8 round-robin) gives each XCD 4
// q-blocks from ALL 32 (b,hf) pairs -> 32 distinct 4.2MB KV streams thrash a
// 4MB L2 (FETCH 84MB vs ~50 ideal). Chunked remap g=(p&7)*4+(p>>8) (bijective)
// gives each XCD exactly 4 (b,hf) streams x 32 lockstep q-blocks -> each KV
// tile enters L2 once, hit 32x. prep_kv/combine unswizzled (no reuse, T1 null).
// Inner loop byte-identical to v14/v20.

__global__ __launch_bounds__(256) void prep_kv(const float* __restrict__ K,
                                               const float* __restrict__ V,
                                               _Float16* __restrict__ Kws,
                                               _Float16* __restrict__ Vws)
{
    int blk = blockIdx.x;
    const int tid = threadIdx.x;
    if (blk < kB * kTiles) {
        // K image: fp16 row-major per tile, with key bits 2<->3 swapped so the
        // 32x32 MFMA S-reg order matches the PV B-operand key order.
        const float* src = K + (size_t)blk * kTileH;
        _Float16* dst = Kws + (size_t)blk * kTileH;
#pragma unroll
        for (int i = 0; i < 2; ++i) {
            const int task = tid + 256 * i;
            const int row  = task >> 3;       // dst physical row 0..63
            const int g    = task & 7;
            const int srow = (row & ~12) | ((row & 4) << 1) | ((row & 8) >> 1);
            const float* p = src + srow * kD + g * 8;
            const float4 a  = *(const float4*)p;
            const float4 b2 = *(const float4*)(p + 4);
            *(half8_t*)(dst + task * 8) = cvt_pk8(a, b2);
        }
    } else {
        // V^T image: [c8 chunk][d][8 keys] halves; natural key order
        blk -= kB * kTiles;
        const float* src = V + (size_t)blk * kTileH;   // [key][d]
        _Float16* dst = Vws + (size_t)blk * kTileH;
        const int d  = tid & 63;
        const int vw = tid >> 6;
#pragma unroll
        for (int i = 0; i < 2; ++i) {
            const int c8 = vw * 2 + i;
            const int k0 = c8 * 8;
            float p[8];
#pragma unroll
            for (int j = 0; j < 8; ++j) p[j] = src[(k0 + j) * kD + d];
            half4_t lo = cvt_pk4(p[0], p[1], p[2], p[3]);
            half4_t hi = cvt_pk4(p[4], p[5], p[6], p[7]);
            *(half8_t*)(dst + (c8 * 64 + d) * 8) = join8(lo, hi);
        }
    }
}

__global__ __launch_bounds__(256, 4)
void fa_fwd(const float* __restrict__ Q, const _Float16* __restrict__ Kws,
            const _Float16* __restrict__ Vws, const float* __restrict__ scale_ptr,
            float* __restrict__ Out, _Float16* __restrict__ O2ws,
            float* __restrict__ Mlws)
{
    __shared__ __align__(16) _Float16 Ksh[2][kBK * kKStride];  // [buf][key_phys][d]
    __shared__ __align__(16) _Float16 Vsh[2][kD * kVStride];   // [buf][d][key] (V^T)

    const int tid  = threadIdx.x;
    const int wave = tid >> 6;
    const int lane = tid & 63;
    const int l31  = lane & 31;   // q-row (QK B / PV B col); key row (QK A); d row (PV A)
    const int hi   = lane >> 5;   // half-select: k = hi*8 + j

    // ---- T1 XCD swizzle: p = dispatch-linear id; XCD(p) = p%8 (round-robin).
    //      XCD x gets g in [4x, 4x+4) => 4 KV streams, 32 lockstep q-blocks each.
    const int p  = blockIdx.x + 32 * blockIdx.y + 512 * blockIdx.z;
    const int qb = (p >> 3) & 31;              // q-block 0..31
    const int g  = (p & 7) * 4 + (p >> 8);     // (b,hf) pair 0..31
    const int b  = g & 15;
    const int hf = g >> 4;                     // key-split half
    const int q0 = qb * kQTile + wave * 32;

    // staging decompositions (match image layouts)
    const int task0 = tid, task1 = tid + 256;          // K: row=task>>3, g=task&7
    const int vd = tid & 63;                           // V: this thread's d
    const int vw = tid >> 6;                           // V: chunk pair base
    const int koff0 = (task0 >> 3) * kKStride + (task0 & 7) * 8;
    const int koff1 = (task1 >> 3) * kKStride + (task1 & 7) * 8;
    const int voff0 = vd * kVStride + (vw * 2 + 0) * 8;
    const int voff1 = vd * kVStride + (vw * 2 + 1) * 8;

    const float qscale = 1.4426950408889634f / scale_ptr[0];

    const float*    Qb = Q   + (size_t)b * kL * kD;
    const _Float16* Kt = Kws + ((size_t)b * kTiles + (size_t)hf * kTilesHf) * kTileH;
    const _Float16* Vt = Vws + ((size_t)b * kTiles + (size_t)hf * kTilesHf) * kTileH;

    // ---- Q fragments (B-operand 32x32x16: n=l31=qrow, k=hi*8+j, d=kd*16+k) ----
    half8_t qfrag[4];
    {
        const float* qrow = Qb + (size_t)(q0 + l31) * kD;
#pragma unroll
        for (int kd = 0; kd < 4; ++kd) {
            const float* pq = qrow + kd * 16 + hi * 8;
            half8_t h;
#pragma unroll
            for (int j = 0; j < 8; ++j) h[j] = (_Float16)(pq[j] * qscale);
            qfrag[kd] = h;
        }
    }

    // O^T accumulators: col=l31=q, row=d=(r&3)+8*(r>>2)+4*hi (+32*dt)
    float16_t O[2];
    O[0] = (float16_t)0.0f;
    O[1] = (float16_t)0.0f;
    float m_run = -__builtin_inff();
    float l_run = 0.0f;   // lane-local (this half's keys); pair-combined in epilogue
    const float16_t Zc = (float16_t)0.0f;

    // ---- prologue: stage tile 0 into buf0, prefetch tile 1 into regs ----
    half8_t kp[2], vp[2];
    kp[0] = *(const half8_t*)(Kt + task0 * 8);
    kp[1] = *(const half8_t*)(Kt + task1 * 8);
    vp[0] = *(const half8_t*)(Vt + ((vw * 2 + 0) * 64 + vd) * 8);
    vp[1] = *(const half8_t*)(Vt + ((vw * 2 + 1) * 64 + vd) * 8);
    *(half8_t*)(&Ksh[0][koff0]) = kp[0];
    *(half8_t*)(&Ksh[0][koff1]) = kp[1];
    *(half8_t*)(&Vsh[0][voff0]) = vp[0];
    *(half8_t*)(&Vsh[0][voff1]) = vp[1];
    {
        const _Float16* kn = Kt + (size_t)1 * kTileH;
        const _Float16* vn = Vt + (size_t)1 * kTileH;
        kp[0] = *(const half8_t*)(kn + task0 * 8);
        kp[1] = *(const half8_t*)(kn + task1 * 8);
        vp[0] = *(const half8_t*)(vn + ((vw * 2 + 0) * 64 + vd) * 8);
        vp[1] = *(const half8_t*)(vn + ((vw * 2 + 1) * 64 + vd) * 8);
    }
    __syncthreads();

    for (int t = 0; t < kTilesHf; ++t) {
        const int cur = t & 1;
        const _Float16* Kb = Ksh[cur];
        const _Float16* Vb = Vsh[cur];
        _Float16* Kn = Ksh[cur ^ 1];
        _Float16* Vn = Vsh[cur ^ 1];

        // ---- commit tile t+1 into the other buffer (overlaps with compute) ----
        *(half8_t*)(&Kn[koff0]) = kp[0];
        *(half8_t*)(&Kn[koff1]) = kp[1];
        *(half8_t*)(&Vn[voff0]) = vp[0];
        *(half8_t*)(&Vn[voff1]) = vp[1];

        // ---- issue global prefetch of tile t+2 (wraps; wrapped data unused) ----
        {
            const int nt = (t + 2) & (kTilesHf - 1);
            const _Float16* kn = Kt + (size_t)nt * kTileH;
            const _Float16* vn = Vt + (size_t)nt * kTileH;
            kp[0] = *(const half8_t*)(kn + task0 * 8);
            kp[1] = *(const half8_t*)(kn + task1 * 8);
            vp[0] = *(const half8_t*)(vn + ((vw * 2 + 0) * 64 + vd) * 8);
            vp[1] = *(const half8_t*)(vn + ((vw * 2 + 1) * 64 + vd) * 8);
        }

        // ---- S^T = K_phys * Q^T : 2 key-blocks x 4 d-chunks of 32x32x16 ----
        float16_t S0, S1;
        {
            half8_t kf0, kf1;
            kf0 = *(const half8_t*)(&Kb[(l31)      * kKStride + 0 * 16 + hi * 8]);
            kf1 = *(const half8_t*)(&Kb[(32 + l31) * kKStride + 0 * 16 + hi * 8]);
            __builtin_amdgcn_s_setprio(1);
            S0 = __builtin_amdgcn_mfma_f32_32x32x16_f16(kf0, qfrag[0], Zc, 0, 0, 0);
            S1 = __builtin_amdgcn_mfma_f32_32x32x16_f16(kf1, qfrag[0], Zc, 0, 0, 0);
#pragma unroll
            for (int kd = 1; kd < 4; ++kd) {
                kf0 = *(const half8_t*)(&Kb[(l31)      * kKStride + kd * 16 + hi * 8]);
                kf1 = *(const half8_t*)(&Kb[(32 + l31) * kKStride + kd * 16 + hi * 8]);
                S0 = __builtin_amdgcn_mfma_f32_32x32x16_f16(kf0, qfrag[kd], S0, 0, 0, 0);
                S1 = __builtin_amdgcn_mfma_f32_32x32x16_f16(kf1, qfrag[kd], S1, 0, 0, 0);
            }
            __builtin_amdgcn_s_setprio(0);
        }

        // ---- online softmax: max3 tree, ONE shfl_xor(32), lane-local l ----
        float v0 = f3(S0[0],  S0[1],  S0[2]);
        float v1 = f3(S0[3],  S0[4],  S0[5]);
        float v2 = f3(S0[6],  S0[7],  S0[8]);
        float v3 = f3(S0[9],  S0[10], S0[11]);
        float v4 = f3(S0[12], S0[13], S0[14]);
        float v5 = f3(S0[15], S1[0],  S1[1]);
        float v6 = f3(S1[2],  S1[3],  S1[4]);
        float v7 = f3(S1[5],  S1[6],  S1[7]);
        float v8 = f3(S1[8],  S1[9],  S1[10]);
        float v9 = f3(S1[11], S1[12], S1[13]);
        float w0 = f3(v0, v1, v2);
        float w1 = f3(v3, v4, v5);
        float w2 = f3(v6, v7, v8);
        float w3 = f3(v9, S1[14], S1[15]);
        float pm = fmaxf(fmaxf(w0, w1), fmaxf(w2, w3));
        pm = fmaxf(pm, __shfl_xor(pm, 32));

        // T13 defer-max: skip rescale while growth <= 8 (P bounded by 2^8, exact)
        const bool need = pm > m_run + 8.0f;
        if (__ballot(need)) {
            const float mn    = fmaxf(m_run, pm);
            const float alpha = __builtin_amdgcn_exp2f(m_run - mn);  // 1st iter: 0
            m_run = mn;
            l_run *= alpha;
#pragma unroll
            for (int r = 0; r < 16; ++r) { O[0][r] *= alpha; O[1][r] *= alpha; }
        }

        // ---- P = exp2(S - m) in place; pack B-fragments; local l sum ----
#pragma unroll
        for (int r = 0; r < 16; ++r) {
            S0[r] = __builtin_amdgcn_exp2f(S0[r] - m_run);
            S1[r] = __builtin_amdgcn_exp2f(S1[r] - m_run);
        }
        half8_t pf[4];
        pf[0] = join8(cvt_pk4(S0[0],  S0[1],  S0[2],  S0[3]),
                      cvt_pk4(S0[4],  S0[5],  S0[6],  S0[7]));
        pf[1] = join8(cvt_pk4(S0[8],  S0[9],  S0[10], S0[11]),
                      cvt_pk4(S0[12], S0[13], S0[14], S0[15]));
        pf[2] = join8(cvt_pk4(S1[0],  S1[1],  S1[2],  S1[3]),
                      cvt_pk4(S1[4],  S1[5],  S1[6],  S1[7]));
        pf[3] = join8(cvt_pk4(S1[8],  S1[9],  S1[10], S1[11]),
                      cvt_pk4(S1[12], S1[13], S1[14], S1[15]));
#define A4(v,a) ((v[a] + v[(a)+1]) + (v[(a)+2] + v[(a)+3]))
        l_run += ((A4(S0, 0) + A4(S0, 4)) + (A4(S0, 8) + A4(S0, 12)))
               + ((A4(S1, 0) + A4(S1, 4)) + (A4(S1, 8) + A4(S1, 12)));
#undef A4

        // ---- O^T += V^T * P : 4 key16-blocks x 2 d-blocks, full-rate x32x16 ----
        __builtin_amdgcn_s_setprio(1);
#pragma unroll
        for (int kb = 0; kb < 4; ++kb) {
            const half8_t vf0 = *(const half8_t*)(
                &Vb[(l31)      * kVStride + kb * 16 + hi * 8]);
            const half8_t vf1 = *(const half8_t*)(
                &Vb[(32 + l31) * kVStride + kb * 16 + hi * 8]);
            O[0] = __builtin_amdgcn_mfma_f32_32x32x16_f16(vf0, pf[kb], O[0], 0, 0, 0);
            O[1] = __builtin_amdgcn_mfma_f32_32x32x16_f16(vf1, pf[kb], O[1], 0, 0, 0);
        }
        __builtin_amdgcn_s_setprio(0);

        // single barrier per tile: reads of buf[cur] done; writes to buf[cur^1] done
        __syncthreads();
    }

    // ---- epilogue: combine lane-pair l; O^T reg r -> d=(r&3)+8*(r>>2)+4*hi+32*dt ----
    l_run += __shfl_xor(l_run, 32);
    const float inv = 1.0f / l_run;
    const int   q   = q0 + l31;
    if (hf == 0) {
        float* op = Out + ((size_t)b * kL + q) * kD;
#pragma unroll
        for (int dt = 0; dt < 2; ++dt)
#pragma unroll
            for (int rr = 0; rr < 4; ++rr) {
                const int d0 = dt * 32 + rr * 8 + hi * 4;
                float4 w;
                w.x = O[dt][rr * 4 + 0] * inv;
                w.y = O[dt][rr * 4 + 1] * inv;
                w.z = O[dt][rr * 4 + 2] * inv;
                w.w = O[dt][rr * 4 + 3] * inv;
                *(float4*)(op + d0) = w;
            }
    } else {
        _Float16* op = O2ws + ((size_t)b * kL + q) * kD;
#pragma unroll
        for (int dt = 0; dt < 2; ++dt)
#pragma unroll
            for (int rr = 0; rr < 4; ++rr) {
                const int d0 = dt * 32 + rr * 8 + hi * 4;
                half4_t w = cvt_pk4(O[dt][rr * 4 + 0] * inv, O[dt][rr * 4 + 1] * inv,
                                    O[dt][rr * 4 + 2] * inv, O[dt][rr * 4 + 3] * inv);
                *(half4_t*)(op + d0) = w;
            }
    }
    if (hi == 0) {
        float2 ml; ml.x = m_run; ml.y = l_run;
        *(float2*)(Mlws + (((size_t)b * kL + q) * 2 + hf) * 2) = ml;
    }
}

// Merge the two key-halves: Out = w1*O1 + w2*O2, w_i = l_i*2^(m_i-m) / sum.
// 2048 blocks x 256 thr, 8 floats/thread (256B-contiguous per 8-lane group).
__global__ __launch_bounds__(256)
void combine(float* __restrict__ Out, const _Float16* __restrict__ O2ws,
             const float* __restrict__ Mlws)
{
    const int t   = threadIdx.x;
    const int row = blockIdx.x * 32 + (t >> 3);   // global row in [0, kB*kL)
    const int d0  = (t & 7) * 8;

    const float m1 = Mlws[(size_t)row * 4 + 0];
    const float l1 = Mlws[(size_t)row * 4 + 1];
    const float m2 = Mlws[(size_t)row * 4 + 2];
    const float l2 = Mlws[(size_t)row * 4 + 3];

    const float m  = fmaxf(m1, m2);
    float w1 = l1 * exp2f(m1 - m);
    float w2 = l2 * exp2f(m2 - m);
    const float inv = 1.0f / (w1 + w2);
    w1 *= inv; w2 *= inv;

    float* op = Out + (size_t)row * kD + d0;
    const _Float16* o2 = O2ws + (size_t)row * kD + d0;
    const half8_t h = *(const half8_t*)o2;
    float4 a = *(const float4*)op;
    float4 c = *(const float4*)(op + 4);
    a.x = a.x * w1 + (float)h[0] * w2;
    a.y = a.y * w1 + (float)h[1] * w2;
    a.z = a.z * w1 + (float)h[2] * w2;
    a.w = a.w * w1 + (float)h[3] * w2;
    c.x = c.x * w1 + (float)h[4] * w2;
    c.y = c.y * w1 + (float)h[5] * w2;
    c.z = c.z * w1 + (float)h[6] * w2;
    c.w = c.w * w1 + (float)h[7] * w2;
    *(float4*)op = a;
    *(float4*)(op + 4) = c;
}

extern "C" void kernel_launch(void* const* d_in, const int* in_sizes, int n_in,
                              void* d_out, int out_size, void* d_ws, size_t ws_size,
                              hipStream_t stream) {
    const float* Q = (const float*)d_in[0];
    const float* K = (const float*)d_in[1];
    const float* V = (const float*)d_in[2];
    const float* s = (const float*)d_in[3];
    float* out = (float*)d_out;
    _Float16* Kws  = (_Float16*)d_ws;
    _Float16* Vws  = Kws + kWsHalves;
    _Float16* O2ws = Vws + kWsHalves;                 // 8.4 MB fp16 partial (half 1)
    float*    Mlws = (float*)(O2ws + kOHalves);       // [b*L][half][{m,l}] = 1.05 MB
    // total ws use: 16.8 + 8.4 + 1.05 = 26.2 MB  (>=34 MB proven in R5)

    prep_kv<<<dim3(2 * kB * kTiles), dim3(256), 0, stream>>>(K, V, Kws, Vws);
    fa_fwd<<<dim3(kL / kQTile, kB, kSplit), dim3(256), 0, stream>>>(Q, Kws, Vws, s, out, O2ws, Mlws);
    combine<<<dim3(kB * kL / 32), dim3(256), 0, stream>>>(out, O2ws, Mlws);
}